// Round 2
// baseline (11702.426 us; speedup 1.0000x reference)
//
#include <hip/hip_runtime.h>
#include <math.h>

#define B_  64
#define T_  1024
#define I_  512
#define O_  512
#define NZ  2048      // 4*O
#define KW  1024      // W row stride (I+O)
#define EPS 1e-5f

#define SREC 32       // recurrent grid: 32 blocks, each owns 16 o-values
#define OSL  16

typedef short bf8_t  __attribute__((ext_vector_type(8)));
typedef float f32x4  __attribute__((ext_vector_type(4)));

__device__ __forceinline__ unsigned short f2bf(float f) {
  union { float f; unsigned u; } v; v.f = f;
  unsigned r = v.u + 0x7FFFu + ((v.u >> 16) & 1u);   // RNE
  return (unsigned short)(r >> 16);
}
__device__ __forceinline__ float bf2f(unsigned short b) {
  union { unsigned u; float f; } v; v.u = ((unsigned)b) << 16;
  return v.f;
}

// ---------------------------------------------------------------------------
// K0: zero counters/flags, init h (bf16) from init_hx
// ---------------------------------------------------------------------------
__global__ __launch_bounds__(256) void init_all(
    const float* __restrict__ init_hx,
    unsigned short* __restrict__ h, unsigned* __restrict__ sync) {
  int idx = blockIdx.x * 256 + threadIdx.x;
  if (idx < 2048) sync[idx] = 0u;
  if (idx < B_ * O_) h[idx] = f2bf(init_hx[idx & (O_ - 1)]);
}

// ---------------------------------------------------------------------------
// K0b: one-time Wx (rows 0..2047, k 0..511) f32 -> bf16.
// Removes 32 f2bf conversions per thread per ks-iter from zx_gemm's hot loop
// (W was being re-converted 1024x per row).
// ---------------------------------------------------------------------------
__global__ __launch_bounds__(256) void wx_bf16(
    const float* __restrict__ W, unsigned short* __restrict__ Wbf) {
  int idx = blockIdx.x * 256 + threadIdx.x;   // one float4 each; 262144 total
  int n  = idx >> 7;                          // 128 float4 per 512-wide row
  int k4 = (idx & 127) * 4;
  float4 v = *(const float4*)(W + (size_t)n * KW + k4);
  unsigned short* d = Wbf + (size_t)n * 512 + k4;
  d[0] = f2bf(v.x); d[1] = f2bf(v.y); d[2] = f2bf(v.z); d[3] = f2bf(v.w);
}

// ---------------------------------------------------------------------------
// K1: zx[b*T+t][n] = x[b][t][:] @ Wx[n][:]   (bf16 MFMA, output bf16)
// B-operand now pre-converted bf16: inner loop = 16B loads + MFMA only.
// ---------------------------------------------------------------------------
__global__ __launch_bounds__(256) void zx_gemm(
    const float* __restrict__ x, const unsigned short* __restrict__ Wbf,
    unsigned short* __restrict__ zx) {
  const int tid  = threadIdx.x;
  const int w    = tid >> 6;
  const int lane = tid & 63;
  const int q    = lane >> 4;
  const int col  = lane & 15;
  const int mblk = blockIdx.x >> 5;   // 0..1023
  const int nblk = blockIdx.x & 31;   // 0..31
  const int m0   = mblk * 64 + w * 16;
  const int n0   = nblk * 64;

  f32x4 acc[4];
  #pragma unroll
  for (int i = 0; i < 4; ++i) acc[i] = (f32x4){0.f, 0.f, 0.f, 0.f};

  const float* __restrict__ arow = x + (size_t)(m0 + col) * I_;

  for (int ks = 0; ks < 16; ++ks) {
    const int k0 = ks * 32 + q * 8;
    float4 a0 = *(const float4*)(arow + k0);
    float4 a1 = *(const float4*)(arow + k0 + 4);
    bf8_t af;
    af[0] = (short)f2bf(a0.x); af[1] = (short)f2bf(a0.y);
    af[2] = (short)f2bf(a0.z); af[3] = (short)f2bf(a0.w);
    af[4] = (short)f2bf(a1.x); af[5] = (short)f2bf(a1.y);
    af[6] = (short)f2bf(a1.z); af[7] = (short)f2bf(a1.w);
    #pragma unroll
    for (int nt = 0; nt < 4; ++nt) {
      bf8_t bfr = *(const bf8_t*)(Wbf + (size_t)(n0 + nt * 16 + col) * 512 + k0);
      acc[nt] = __builtin_amdgcn_mfma_f32_16x16x32_bf16(af, bfr, acc[nt], 0, 0, 0);
    }
  }
  // C/D layout: col = lane&15, row = (lane>>4)*4 + reg  [verified m89]
  #pragma unroll
  for (int nt = 0; nt < 4; ++nt)
    #pragma unroll
    for (int r = 0; r < 4; ++r) {
      int m = m0 + 4 * q + r;
      zx[(size_t)m * NZ + n0 + nt * 16 + col] = f2bf(acc[nt][r]);
    }
}

// ---------------------------------------------------------------------------
// K2: recurrent loop. 32 blocks; block s owns o in [16s,16s+16) across all
// 4 gates. Wh slice bf16 in LDS (staged once). c stays in registers.
//
// Sync (this round): single-line counter barriers, fence-free.
//  - cnt1/cnt2: one fetch_add per block per step (monotonic, target 32*(t+1)).
//    All threads poll a WAVE-UNIFORM address -> 1 LLC request per wave-poll
//    (R1's flag array was a 32-line gather per wave-poll).
//  - __syncthreads() before the add drains vmcnt(0) for every wave, ordering
//    all sc1 data stores before the arrive (validated protocol, R1).
//  - LN reduce distributed per-wave: part8 laid out b-major; lane loads 8
//    contiguous partials, shfl_xor x2 combines quarters, shfl broadcasts
//    mean/rstd. No wave0-serial phase, no LDS round, no extra syncthreads.
//  - out stores + zx(t+1) prefetch issue in bar2's spin shadow.
// ---------------------------------------------------------------------------
__global__ __launch_bounds__(256) void lstm_rec(
    const float* __restrict__ W, const float* __restrict__ gamma,
    const float* __restrict__ beta, const float* __restrict__ init_cx,
    const unsigned short* __restrict__ zx, unsigned short* __restrict__ h,
    unsigned long long* __restrict__ part8, float* __restrict__ out,
    unsigned* __restrict__ flags) {

  __shared__ unsigned short whlds[64 * 520];   // 64 rows (g*16+n'), pad 512->520

  const int tid  = threadIdx.x;
  const int w    = tid >> 6;
  const int lane = tid & 63;
  const int q    = lane >> 4;
  const int col  = lane & 15;
  const int s    = blockIdx.x;
  const int o    = s * OSL + col;

  // ---- stage Wh slice -> LDS (once)
  for (int e4 = tid; e4 < 64 * 128; e4 += 256) {
    int r  = e4 >> 7;            // row 0..63
    int k4 = (e4 & 127) * 4;     // k 0..508
    int g  = r >> 4, np = r & 15;
    const float4 v =
        *(const float4*)(W + (size_t)(512 * g + OSL * s + np) * KW + I_ + k4);
    unsigned short* d = &whlds[r * 520 + k4];
    d[0] = f2bf(v.x); d[1] = f2bf(v.y); d[2] = f2bf(v.z); d[3] = f2bf(v.w);
  }

  float gma[4], bta[4], c_reg[4];
  #pragma unroll
  for (int g = 0; g < 4; ++g) { gma[g] = gamma[g * O_ + o]; bta[g] = beta[g * O_ + o]; }
  { float c0 = init_cx[o];
    #pragma unroll
    for (int r = 0; r < 4; ++r) c_reg[r] = c0; }

  unsigned* cnt1 = flags;        // arrive counter, barrier 1
  unsigned* cnt2 = flags + 64;   // arrive counter, barrier 2 (separate line)

  // ---- prologue: prefetch zx for t=0
  unsigned short zxl[16];
  #pragma unroll
  for (int g = 0; g < 4; ++g)
    #pragma unroll
    for (int r = 0; r < 4; ++r) {
      int b = 16 * w + 4 * q + r;
      zxl[g * 4 + r] = zx[((size_t)b * T_ + 0) * NZ + g * O_ + OSL * s + col];
    }

  __syncthreads();

  for (int t = 0; t < T_; ++t) {
    // ---- prefetch full h fragment set (sc1 read-through; fresh after bar2)
    unsigned long long araw[32];
    const unsigned short* hrow = h + (16 * w + col) * O_;
    #pragma unroll
    for (int ks = 0; ks < 16; ++ks) {
      const unsigned long long* p =
          (const unsigned long long*)(hrow + ks * 32 + q * 8);
      araw[2 * ks]     = __hip_atomic_load(p,     __ATOMIC_RELAXED, __HIP_MEMORY_SCOPE_AGENT);
      araw[2 * ks + 1] = __hip_atomic_load(p + 1, __ATOMIC_RELAXED, __HIP_MEMORY_SCOPE_AGENT);
    }

    // ---- z-slice = h @ Wh^T  (16x16x32 bf16 MFMA; wave w -> rows 16w..16w+15)
    f32x4 acc[4];
    #pragma unroll
    for (int g = 0; g < 4; ++g) acc[g] = (f32x4){0.f, 0.f, 0.f, 0.f};

    #pragma unroll
    for (int ks = 0; ks < 16; ++ks) {
      union { unsigned long long u[2]; bf8_t v; } au;
      au.u[0] = araw[2 * ks]; au.u[1] = araw[2 * ks + 1];
      #pragma unroll
      for (int g = 0; g < 4; ++g) {
        bf8_t bfr = *(const bf8_t*)(&whlds[(g * 16 + col) * 520 + ks * 32 + q * 8]);
        acc[g] = __builtin_amdgcn_mfma_f32_16x16x32_bf16(au.v, bfr, acc[g], 0, 0, 0);
      }
    }

    // ---- z = acc + zx; block-partial LN sums per batch row
    float z[16];
    float s1[4], s2[4];
    #pragma unroll
    for (int r = 0; r < 4; ++r) { s1[r] = 0.f; s2[r] = 0.f; }
    #pragma unroll
    for (int g = 0; g < 4; ++g)
      #pragma unroll
      for (int r = 0; r < 4; ++r) {
        float zv = acc[g][r] + bf2f(zxl[g * 4 + r]);
        z[g * 4 + r] = zv;
        s1[r] += zv;
        s2[r] += zv * zv;
      }
    #pragma unroll
    for (int m = 1; m < 16; m <<= 1) {
      #pragma unroll
      for (int r = 0; r < 4; ++r) {
        s1[r] += __shfl_xor(s1[r], m, 64);
        s2[r] += __shfl_xor(s2[r], m, 64);
      }
    }
    if (col == 0) {
      #pragma unroll
      for (int r = 0; r < 4; ++r) {
        int b = 16 * w + 4 * q + r;
        union { float f[2]; unsigned long long u; } pv;
        pv.f[0] = s1[r]; pv.f[1] = s2[r];
        __hip_atomic_store(&part8[(size_t)b * SREC + s], pv.u,
                           __ATOMIC_RELAXED, __HIP_MEMORY_SCOPE_AGENT);
      }
    }

    // ---- barrier 1: partials ready (arrive after full-block drain, then poll)
    __syncthreads();   // drains vmcnt(0) for all waves -> partials at LLC
    if (tid == 0)
      __hip_atomic_fetch_add(cnt1, 1u, __ATOMIC_RELAXED, __HIP_MEMORY_SCOPE_AGENT);
    {
      const unsigned tgt = (unsigned)(t + 1) * SREC;
      while (__hip_atomic_load(cnt1, __ATOMIC_RELAXED, __HIP_MEMORY_SCOPE_AGENT) < tgt) {}
    }

    // ---- distributed LN reduce: lane handles row 16w+(lane&15), 8 blocks
    float S1 = 0.f, S2 = 0.f;
    {
      const int brow = 16 * w + (lane & 15);
      const unsigned long long* pp = &part8[(size_t)brow * SREC + (lane >> 4) * 8];
      #pragma unroll
      for (int i = 0; i < 8; ++i) {
        union { float f[2]; unsigned long long u; } pv;
        pv.u = __hip_atomic_load(pp + i, __ATOMIC_RELAXED, __HIP_MEMORY_SCOPE_AGENT);
        S1 += pv.f[0]; S2 += pv.f[1];
      }
    }
    S1 += __shfl_xor(S1, 16, 64); S2 += __shfl_xor(S2, 16, 64);
    S1 += __shfl_xor(S1, 32, 64); S2 += __shfl_xor(S2, 32, 64);
    float mean_l = S1 * (1.f / NZ);
    float rstd_l = rsqrtf(S2 * (1.f / NZ) - mean_l * mean_l + EPS);

    // ---- gates + state update (mean/rstd pulled from lane 4q+r)
    float hnl[4];
    #pragma unroll
    for (int r = 0; r < 4; ++r) {
      int b = 16 * w + 4 * q + r;
      float mean = __shfl(mean_l, 4 * q + r, 64);
      float rstd = __shfl(rstd_l, 4 * q + r, 64);
      float zn0 = (z[0 * 4 + r] - mean) * rstd * gma[0] + bta[0];
      float zn1 = (z[1 * 4 + r] - mean) * rstd * gma[1] + bta[1];
      float zn2 = (z[2 * 4 + r] - mean) * rstd * gma[2] + bta[2];
      float zn3 = (z[3 * 4 + r] - mean) * rstd * gma[3] + bta[3];
      float fg = 1.f / (1.f + expf(-zn0));
      float ig = 1.f / (1.f + expf(-zn1));
      float og = 1.f / (1.f + expf(-zn2));
      float gg = 0.5f * zn3 * (1.f + erff(zn3 * 0.70710678118654752f));
      float cn = fg * c_reg[r] + ig * gg;
      float hn = og * cn;
      c_reg[r] = cn;
      hnl[r] = hn;
      __hip_atomic_store(&h[b * O_ + o], f2bf(hn),
                         __ATOMIC_RELAXED, __HIP_MEMORY_SCOPE_AGENT);
    }

    // ---- barrier 2: h ready. out stores + zx prefetch live in the shadow.
    if (t + 1 < T_) {
      __syncthreads();   // drains vmcnt(0) -> h stores at LLC
      if (tid == 0)
        __hip_atomic_fetch_add(cnt2, 1u, __ATOMIC_RELAXED, __HIP_MEMORY_SCOPE_AGENT);
      #pragma unroll
      for (int r = 0; r < 4; ++r) {
        int b = 16 * w + 4 * q + r;
        out[((size_t)b * T_ + t) * O_ + o] = hnl[r];
      }
      #pragma unroll
      for (int g = 0; g < 4; ++g)
        #pragma unroll
        for (int r = 0; r < 4; ++r) {
          int b = 16 * w + 4 * q + r;
          zxl[g * 4 + r] =
              zx[((size_t)b * T_ + (t + 1)) * NZ + g * O_ + OSL * s + col];
        }
      const unsigned tgt = (unsigned)(t + 1) * SREC;
      while (__hip_atomic_load(cnt2, __ATOMIC_RELAXED, __HIP_MEMORY_SCOPE_AGENT) < tgt) {}
    } else {
      #pragma unroll
      for (int r = 0; r < 4; ++r) {
        int b = 16 * w + 4 * q + r;
        out[((size_t)b * T_ + t) * O_ + o] = hnl[r];
      }
    }
  }
}

// ---------------------------------------------------------------------------
extern "C" void kernel_launch(void* const* d_in, const int* in_sizes, int n_in,
                              void* d_out, int out_size, void* d_ws, size_t ws_size,
                              hipStream_t stream) {
  const float* x       = (const float*)d_in[0];
  const float* W       = (const float*)d_in[1];
  const float* gamma   = (const float*)d_in[2];
  const float* beta    = (const float*)d_in[3];
  const float* init_hx = (const float*)d_in[4];
  const float* init_cx = (const float*)d_in[5];
  float* out = (float*)d_out;
  (void)in_sizes; (void)n_in; (void)out_size; (void)ws_size;

  char* ws = (char*)d_ws;
  unsigned*           flags = (unsigned*)(ws);                        // 8 KB zeroed
  unsigned long long* part8 = (unsigned long long*)(ws + 8192);       // 16 KB
  unsigned short*     h     = (unsigned short*)(ws + 32768);          // 64 KB
  unsigned short*     Wbf   = (unsigned short*)(ws + (1 << 20));      // 2 MB
  unsigned short*     zx    = (unsigned short*)(ws + (4 << 20));      // 256 MB

  init_all<<<128, 256, 0, stream>>>(init_hx, h, flags);
  wx_bf16<<<1024, 256, 0, stream>>>(W, Wbf);
  zx_gemm<<<32768, 256, 0, stream>>>(x, Wbf, zx);
  lstm_rec<<<SREC, 256, 0, stream>>>(W, gamma, beta, init_cx, zx, h, part8, out, flags);
}

// Round 3
// 9485.880 us; speedup vs baseline: 1.2337x; 1.2337x over previous
//
#include <hip/hip_runtime.h>
#include <math.h>

#define B_  64
#define T_  1024
#define I_  512
#define O_  512
#define NZ  2048      // 4*O
#define KW  1024      // W row stride (I+O)
#define EPS 1e-5f

#define SREC 32       // recurrent grid: 32 blocks, each owns 16 o-values
#define OSL  16

typedef short bf8_t  __attribute__((ext_vector_type(8)));
typedef float f32x4  __attribute__((ext_vector_type(4)));

__device__ __forceinline__ unsigned short f2bf(float f) {
  union { float f; unsigned u; } v; v.f = f;
  unsigned r = v.u + 0x7FFFu + ((v.u >> 16) & 1u);   // RNE
  return (unsigned short)(r >> 16);
}
__device__ __forceinline__ float bf2f(unsigned short b) {
  union { unsigned u; float f; } v; v.u = ((unsigned)b) << 16;
  return v.f;
}

// ---------------------------------------------------------------------------
// K0: zero flag slots, init h (bf16) from init_hx
// ---------------------------------------------------------------------------
__global__ __launch_bounds__(256) void init_all(
    const float* __restrict__ init_hx,
    unsigned short* __restrict__ h, unsigned* __restrict__ sync) {
  int idx = blockIdx.x * 256 + threadIdx.x;
  if (idx < 2048) sync[idx] = 0u;
  if (idx < B_ * O_) h[idx] = f2bf(init_hx[idx & (O_ - 1)]);
}

// ---------------------------------------------------------------------------
// K0b: one-time Wx (rows 0..2047, k 0..511) f32 -> bf16. (kept from R2)
// ---------------------------------------------------------------------------
__global__ __launch_bounds__(256) void wx_bf16(
    const float* __restrict__ W, unsigned short* __restrict__ Wbf) {
  int idx = blockIdx.x * 256 + threadIdx.x;   // one float4 each; 262144 total
  int n  = idx >> 7;                          // 128 float4 per 512-wide row
  int k4 = (idx & 127) * 4;
  float4 v = *(const float4*)(W + (size_t)n * KW + k4);
  unsigned short* d = Wbf + (size_t)n * 512 + k4;
  d[0] = f2bf(v.x); d[1] = f2bf(v.y); d[2] = f2bf(v.z); d[3] = f2bf(v.w);
}

// ---------------------------------------------------------------------------
// K1 (rewritten): zx[b*T+t][n] = x[b][t][:] @ Wx[n][:]
// One block per 64-row m-tile; x-tile converted to bf16 in LDS ONCE, then all
// 32 n-blocks computed inside the block. Kills the 32x HBM re-stream of x
// (4.3 GB -> 134 MB); Wbf (2 MB) is L2-resident per XCD.
// ---------------------------------------------------------------------------
__global__ __launch_bounds__(256) void zx_gemm(
    const float* __restrict__ x, const unsigned short* __restrict__ Wbf,
    unsigned short* __restrict__ zx) {
  __shared__ unsigned short xl[64 * 520];     // 64 rows x 512 bf16 (+8 pad)

  const int tid  = threadIdx.x;
  const int w    = tid >> 6;
  const int lane = tid & 63;
  const int q    = lane >> 4;
  const int col  = lane & 15;
  const int m0   = blockIdx.x * 64;           // 1024 blocks

  // stage x-tile -> LDS bf16
  for (int e4 = tid; e4 < 64 * 128; e4 += 256) {
    int r  = e4 >> 7;
    int k4 = (e4 & 127) * 4;
    float4 v = *(const float4*)(x + (size_t)(m0 + r) * I_ + k4);
    unsigned short* d = &xl[r * 520 + k4];
    d[0] = f2bf(v.x); d[1] = f2bf(v.y); d[2] = f2bf(v.z); d[3] = f2bf(v.w);
  }
  __syncthreads();

  const unsigned short* __restrict__ arow = &xl[(16 * w + col) * 520];

  for (int nblk = 0; nblk < 32; ++nblk) {
    const int n0 = nblk * 64;
    f32x4 acc[4];
    #pragma unroll
    for (int i = 0; i < 4; ++i) acc[i] = (f32x4){0.f, 0.f, 0.f, 0.f};

    #pragma unroll
    for (int ks = 0; ks < 16; ++ks) {
      const int k0 = ks * 32 + q * 8;
      bf8_t af = *(const bf8_t*)(arow + k0);
      #pragma unroll
      for (int nt = 0; nt < 4; ++nt) {
        bf8_t bfr = *(const bf8_t*)(Wbf + (size_t)(n0 + nt * 16 + col) * 512 + k0);
        acc[nt] = __builtin_amdgcn_mfma_f32_16x16x32_bf16(af, bfr, acc[nt], 0, 0, 0);
      }
    }
    // C/D layout: col = lane&15, row = (lane>>4)*4 + reg  [verified m89]
    #pragma unroll
    for (int nt = 0; nt < 4; ++nt)
      #pragma unroll
      for (int r = 0; r < 4; ++r) {
        int m = m0 + 16 * w + 4 * q + r;
        zx[(size_t)m * NZ + n0 + nt * 16 + col] = f2bf(acc[nt][r]);
      }
  }
}

// ---------------------------------------------------------------------------
// K2: recurrent loop. 32 blocks; block s owns o in [16s,16s+16) across all
// 4 gates. Wh slice bf16 in LDS (staged once). c stays in registers.
//
// Sync: R1's validated flag-array barrier (restored after R2 regression).
//  - arrive: plain sc1 store of monotonic value to block-private flag line.
//    NO RMW: R2's single-counter fetch_add serialized against 128 polling
//    waves on one LLC line (-1.8 ms).
//  - poll: every thread loads flags[(tid&31)*16] -> one vector load per wave
//    gathers all 32 flags across 32 LLC lines in parallel; wave exits when
//    all lanes (= all blocks) satisfied.
//  - __syncthreads() before arrive drains vmcnt(0) for every wave (release).
//  - part8 s-major (coalesced 8-line writes per block).
//  - distributed LN reduce (per-wave, shfl) kept from R2.
//  - out stores + zx(t+1) prefetch in bar2's shadow (arrive -> work -> poll).
// ---------------------------------------------------------------------------
__global__ __launch_bounds__(256) void lstm_rec(
    const float* __restrict__ W, const float* __restrict__ gamma,
    const float* __restrict__ beta, const float* __restrict__ init_cx,
    const unsigned short* __restrict__ zx, unsigned short* __restrict__ h,
    unsigned long long* __restrict__ part8, float* __restrict__ out,
    unsigned* __restrict__ flags) {

  __shared__ unsigned short whlds[64 * 520];   // 64 rows (g*16+n'), pad 512->520

  const int tid  = threadIdx.x;
  const int w    = tid >> 6;
  const int lane = tid & 63;
  const int q    = lane >> 4;
  const int col  = lane & 15;
  const int s    = blockIdx.x;
  const int o    = s * OSL + col;

  // ---- stage Wh slice -> LDS (once)
  for (int e4 = tid; e4 < 64 * 128; e4 += 256) {
    int r  = e4 >> 7;            // row 0..63
    int k4 = (e4 & 127) * 4;     // k 0..508
    int g  = r >> 4, np = r & 15;
    const float4 v =
        *(const float4*)(W + (size_t)(512 * g + OSL * s + np) * KW + I_ + k4);
    unsigned short* d = &whlds[r * 520 + k4];
    d[0] = f2bf(v.x); d[1] = f2bf(v.y); d[2] = f2bf(v.z); d[3] = f2bf(v.w);
  }

  float gma[4], bta[4], c_reg[4];
  #pragma unroll
  for (int g = 0; g < 4; ++g) { gma[g] = gamma[g * O_ + o]; bta[g] = beta[g * O_ + o]; }
  { float c0 = init_cx[o];
    #pragma unroll
    for (int r = 0; r < 4; ++r) c_reg[r] = c0; }

  // ---- prologue: prefetch zx for t=0
  unsigned short zxl[16];
  #pragma unroll
  for (int g = 0; g < 4; ++g)
    #pragma unroll
    for (int r = 0; r < 4; ++r) {
      int b = 16 * w + 4 * q + r;
      zxl[g * 4 + r] = zx[((size_t)b * T_ + 0) * NZ + g * O_ + OSL * s + col];
    }

  __syncthreads();

  for (int t = 0; t < T_; ++t) {
    // ---- gather full h fragment set (sc1 read-through; fresh after bar2)
    unsigned long long araw[32];
    const unsigned short* hrow = h + (16 * w + col) * O_;
    #pragma unroll
    for (int ks = 0; ks < 16; ++ks) {
      const unsigned long long* p =
          (const unsigned long long*)(hrow + ks * 32 + q * 8);
      araw[2 * ks]     = __hip_atomic_load(p,     __ATOMIC_RELAXED, __HIP_MEMORY_SCOPE_AGENT);
      araw[2 * ks + 1] = __hip_atomic_load(p + 1, __ATOMIC_RELAXED, __HIP_MEMORY_SCOPE_AGENT);
    }

    // ---- z-slice = h @ Wh^T  (16x16x32 bf16 MFMA; wave w -> rows 16w..16w+15)
    f32x4 acc[4];
    #pragma unroll
    for (int g = 0; g < 4; ++g) acc[g] = (f32x4){0.f, 0.f, 0.f, 0.f};

    #pragma unroll
    for (int ks = 0; ks < 16; ++ks) {
      union { unsigned long long u[2]; bf8_t v; } au;
      au.u[0] = araw[2 * ks]; au.u[1] = araw[2 * ks + 1];
      #pragma unroll
      for (int g = 0; g < 4; ++g) {
        bf8_t bfr = *(const bf8_t*)(&whlds[(g * 16 + col) * 520 + ks * 32 + q * 8]);
        acc[g] = __builtin_amdgcn_mfma_f32_16x16x32_bf16(au.v, bfr, acc[g], 0, 0, 0);
      }
    }

    // ---- z = acc + zx; block-partial LN sums per batch row
    float z[16];
    float s1[4], s2[4];
    #pragma unroll
    for (int r = 0; r < 4; ++r) { s1[r] = 0.f; s2[r] = 0.f; }
    #pragma unroll
    for (int g = 0; g < 4; ++g)
      #pragma unroll
      for (int r = 0; r < 4; ++r) {
        float zv = acc[g][r] + bf2f(zxl[g * 4 + r]);
        z[g * 4 + r] = zv;
        s1[r] += zv;
        s2[r] += zv * zv;
      }
    #pragma unroll
    for (int m = 1; m < 16; m <<= 1) {
      #pragma unroll
      for (int r = 0; r < 4; ++r) {
        s1[r] += __shfl_xor(s1[r], m, 64);
        s2[r] += __shfl_xor(s2[r], m, 64);
      }
    }
    if (col == 0) {
      #pragma unroll
      for (int r = 0; r < 4; ++r) {
        int b = 16 * w + 4 * q + r;
        union { float f[2]; unsigned long long u; } pv;
        pv.f[0] = s1[r]; pv.f[1] = s2[r];
        __hip_atomic_store(&part8[(size_t)s * 64 + b], pv.u,
                           __ATOMIC_RELAXED, __HIP_MEMORY_SCOPE_AGENT);
      }
    }

    // ---- barrier 1: partials ready
    __syncthreads();   // drains vmcnt(0) for all waves -> partials at LLC
    {
      const unsigned tgt = 2u * (unsigned)t + 1u;
      if (tid == 0)
        __hip_atomic_store(&flags[s * 16], tgt,
                           __ATOMIC_RELAXED, __HIP_MEMORY_SCOPE_AGENT);
      const unsigned* fp = &flags[(tid & 31) * 16];
      while (__hip_atomic_load(fp, __ATOMIC_RELAXED, __HIP_MEMORY_SCOPE_AGENT) < tgt) {}
    }

    // ---- distributed LN reduce: lane owns brow = 16w+(lane&15); 8 s-chunks
    float S1 = 0.f, S2 = 0.f;
    {
      const int brow = 16 * w + (lane & 15);
      const int sbase = (lane >> 4) * 8;
      #pragma unroll
      for (int i = 0; i < 8; ++i) {
        union { float f[2]; unsigned long long u; } pv;
        pv.u = __hip_atomic_load(&part8[(size_t)(sbase + i) * 64 + brow],
                                 __ATOMIC_RELAXED, __HIP_MEMORY_SCOPE_AGENT);
        S1 += pv.f[0]; S2 += pv.f[1];
      }
    }
    S1 += __shfl_xor(S1, 16, 64); S2 += __shfl_xor(S2, 16, 64);
    S1 += __shfl_xor(S1, 32, 64); S2 += __shfl_xor(S2, 32, 64);
    float mean_l = S1 * (1.f / NZ);
    float rstd_l = rsqrtf(S2 * (1.f / NZ) - mean_l * mean_l + EPS);

    // ---- gates + state update (mean/rstd pulled from lane 4q+r)
    float hnl[4];
    #pragma unroll
    for (int r = 0; r < 4; ++r) {
      int b = 16 * w + 4 * q + r;
      float mean = __shfl(mean_l, 4 * q + r, 64);
      float rstd = __shfl(rstd_l, 4 * q + r, 64);
      float zn0 = (z[0 * 4 + r] - mean) * rstd * gma[0] + bta[0];
      float zn1 = (z[1 * 4 + r] - mean) * rstd * gma[1] + bta[1];
      float zn2 = (z[2 * 4 + r] - mean) * rstd * gma[2] + bta[2];
      float zn3 = (z[3 * 4 + r] - mean) * rstd * gma[3] + bta[3];
      float fg = 1.f / (1.f + expf(-zn0));
      float ig = 1.f / (1.f + expf(-zn1));
      float og = 1.f / (1.f + expf(-zn2));
      float gg = 0.5f * zn3 * (1.f + erff(zn3 * 0.70710678118654752f));
      float cn = fg * c_reg[r] + ig * gg;
      float hn = og * cn;
      c_reg[r] = cn;
      hnl[r] = hn;
      __hip_atomic_store(&h[b * O_ + o], f2bf(hn),
                         __ATOMIC_RELAXED, __HIP_MEMORY_SCOPE_AGENT);
    }

    // ---- barrier 2: h ready. out stores + zx prefetch live in the shadow.
    if (t + 1 < T_) {
      __syncthreads();   // drains vmcnt(0) -> h stores at LLC
      const unsigned tgt = 2u * (unsigned)t + 2u;
      if (tid == 0)
        __hip_atomic_store(&flags[s * 16], tgt,
                           __ATOMIC_RELAXED, __HIP_MEMORY_SCOPE_AGENT);
      #pragma unroll
      for (int r = 0; r < 4; ++r) {
        int b = 16 * w + 4 * q + r;
        out[((size_t)b * T_ + t) * O_ + o] = hnl[r];
      }
      #pragma unroll
      for (int g = 0; g < 4; ++g)
        #pragma unroll
        for (int r = 0; r < 4; ++r) {
          int b = 16 * w + 4 * q + r;
          zxl[g * 4 + r] =
              zx[((size_t)b * T_ + (t + 1)) * NZ + g * O_ + OSL * s + col];
        }
      const unsigned* fp = &flags[(tid & 31) * 16];
      while (__hip_atomic_load(fp, __ATOMIC_RELAXED, __HIP_MEMORY_SCOPE_AGENT) < tgt) {}
    } else {
      #pragma unroll
      for (int r = 0; r < 4; ++r) {
        int b = 16 * w + 4 * q + r;
        out[((size_t)b * T_ + t) * O_ + o] = hnl[r];
      }
    }
  }
}

// ---------------------------------------------------------------------------
extern "C" void kernel_launch(void* const* d_in, const int* in_sizes, int n_in,
                              void* d_out, int out_size, void* d_ws, size_t ws_size,
                              hipStream_t stream) {
  const float* x       = (const float*)d_in[0];
  const float* W       = (const float*)d_in[1];
  const float* gamma   = (const float*)d_in[2];
  const float* beta    = (const float*)d_in[3];
  const float* init_hx = (const float*)d_in[4];
  const float* init_cx = (const float*)d_in[5];
  float* out = (float*)d_out;
  (void)in_sizes; (void)n_in; (void)out_size; (void)ws_size;

  char* ws = (char*)d_ws;
  unsigned*           flags = (unsigned*)(ws);                        // 8 KB zeroed
  unsigned long long* part8 = (unsigned long long*)(ws + 8192);       // 16 KB
  unsigned short*     h     = (unsigned short*)(ws + 32768);          // 64 KB
  unsigned short*     Wbf   = (unsigned short*)(ws + (1 << 20));      // 2 MB
  unsigned short*     zx    = (unsigned short*)(ws + (4 << 20));      // 256 MB

  init_all<<<128, 256, 0, stream>>>(init_hx, h, flags);
  wx_bf16<<<1024, 256, 0, stream>>>(W, Wbf);
  zx_gemm<<<1024, 256, 0, stream>>>(x, Wbf, zx);
  lstm_rec<<<SREC, 256, 0, stream>>>(W, gamma, beta, init_cx, zx, h, part8, out, flags);
}